// Round 25
// baseline (185.299 us; speedup 1.0000x reference)
//
#include <hip/hip_runtime.h>
#include <hip/hip_fp16.h>
#include <math.h>

// Problem constants (from reference)
#define BATCH 128
#define NI    1152
#define ND    8
#define NC    32
#define NE    16
#define NROUT 3

// r24 pipeline (proven 105 us) with double-buffered group staging:
// GT=3 tiles/group, 2 LDS buffers (2x26.1KB = 52.2KB, same 3 blocks/CU).
// Group g+2's global loads issued before the lgkm-only barrier (counted
// vmcnt survives it); g+1's regs written to the spare buffer after
// compute(g). Staging latency hides under a full group of compute.
#define ISPLIT     48
#define GT         3                // tiles per group
#define BT         8
#define NB         2
#define RT_THREADS 256
#define CROW       68               // words per c row (4c mod 32 -> uniform banks)
#define TLDSW      (NC * CROW)      // 2176 words per padded tile (8704 B)
#define SQ_THREADS 256
#define PREP_TPB   2

typedef _Float16 h2 __attribute__((ext_vector_type(2)));
typedef unsigned int uint;

__device__ __forceinline__ h2 cvt_pk(float a, float b) {
    auto r = __builtin_amdgcn_cvt_pkrtz(a, b);
    union { decltype(r) i; h2 o; } u; u.i = r; return u.o;
}
__device__ __forceinline__ uint h2u(h2 v) { union { h2 h; uint u; } x; x.h = v; return x.u; }
__device__ __forceinline__ h2 u2h(uint v) { union { uint u; h2 h; } x; x.u = v; return x.h; }

#if __has_builtin(__builtin_amdgcn_fdot2)
#define FDOT2(a, b, c) __builtin_amdgcn_fdot2((a), (b), (c), false)
#else
__device__ __forceinline__ float FDOT2(h2 a, h2 b, float c) {
    return c + (float)a.x * (float)b.x + (float)a.y * (float)b.y;
}
#endif

template<int CTRL>
__device__ __forceinline__ float dpp_add(float v) {
    int t = __builtin_amdgcn_update_dpp(0, __float_as_int(v), CTRL, 0xF, 0xF, true);
    return v + __int_as_float(t);
}

__device__ __forceinline__ float xor32_sum(float v) {
#if __has_builtin(__builtin_amdgcn_permlane32_swap)
    auto r = __builtin_amdgcn_permlane32_swap(__float_as_int(v), __float_as_int(v), false, false);
    return __int_as_float(r[0]) + __int_as_float(r[1]);
#else
    return v + __shfl_xor(v, 32);
#endif
}
__device__ __forceinline__ float xor16_sum(float v) {
#if __has_builtin(__builtin_amdgcn_permlane16_swap)
    auto r = __builtin_amdgcn_permlane16_swap(__float_as_int(v), __float_as_int(v), false, false);
    return __int_as_float(r[0]) + __int_as_float(r[1]);
#else
    int s = __builtin_amdgcn_ds_swizzle(__float_as_int(v), 0x401F);
    return v + __int_as_float(s);
#endif
}

__device__ __forceinline__ float sum_over_e8(float v) {
    v = dpp_add<0xB1>(v);
    v = dpp_add<0x4E>(v);
    v = dpp_add<0x141>(v);
    return v;
}

// LDS-ordered barrier that does NOT drain vmcnt: in-flight global loads
// survive it (counted vmcnt waits appear only at their register uses).
__device__ __forceinline__ void lds_barrier() {
    asm volatile("s_waitcnt lgkmcnt(0)" ::: "memory");
    __builtin_amdgcn_s_barrier();
    __builtin_amdgcn_sched_barrier(0);
}

// ---------------------------------------------------------------------------
// prep: W[i][c][d][e] fp32 -> padded fp16 tile image (word c*68 + e*4 + dp).
// ---------------------------------------------------------------------------
__global__ __launch_bounds__(RT_THREADS)
void prep_kernel(const float* __restrict__ W, uint* __restrict__ W_hp)
{
    __shared__ float ls[PREP_TPB][NC * 132];

    const int tid = threadIdx.x;
    const size_t i0 = (size_t)blockIdx.x * PREP_TPB;

    const float4* src = (const float4*)(W + i0 * (NC * ND * NE));
#pragma unroll
    for (int t = 0; t < PREP_TPB; ++t) {
#pragma unroll
        for (int r = 0; r < 4; ++r) {
            int g = tid + r * RT_THREADS;
            float4 v = src[t * 1024 + g];
            *(float4*)&ls[t][(g >> 5) * 132 + (g & 31) * 4] = v;
        }
    }
    __syncthreads();

#pragma unroll
    for (int t = 0; t < PREP_TPB; ++t) {
#pragma unroll
        for (int r = 0; r < 2; ++r) {
            int g = tid + r * RT_THREADS;
            int c = g >> 4, e = g & 15;
            const float* p = &ls[t][c * 132 + e];
            uint4 o;
            o.x = h2u(cvt_pk(p[0],  p[16]));
            o.y = h2u(cvt_pk(p[32], p[48]));
            o.z = h2u(cvt_pk(p[64], p[80]));
            o.w = h2u(cvt_pk(p[96], p[112]));
            *(uint4*)&W_hp[(i0 + t) * TLDSW + c * CROW + e * 4] = o;
        }
    }
}

// ---------------------------------------------------------------------------
// route: double-buffered 3-tile groups with pipelined staging; barrier-free
// dot2 bodies (NB=2), all-VALU softmax, fp16 partial s out.
// ---------------------------------------------------------------------------
__global__ __launch_bounds__(RT_THREADS)
void route_iter_kernel(const float* __restrict__ x, const uint* __restrict__ W_hp,
                       const float* __restrict__ o_sum, __half* __restrict__ s_part,
                       int iter)
{
    constexpr int ICHUNK_T = NI / ISPLIT;          // 24
    constexpr int NG       = ICHUNK_T / GT;        // 8 groups
    constexpr int TOT4     = GT * TLDSW / 4;       // 1632 uint4 per group
    constexpr int LPT      = (TOT4 + RT_THREADS - 1) / RT_THREADS;  // 7
    static_assert(NG * GT == ICHUNK_T, "group split");

    __shared__ uint Wh[2][GT * TLDSW];             // 2 x 26,112 B = 52,224 B

    const int tid = threadIdx.x;
    const int c   = tid & 31;
    const int eh  = (tid >> 5) & 1;
    int wid;   // laundered wave id -> x addresses stay on the vector path
    asm("v_mov_b32 %0, %1" : "=v"(wid) : "v"(tid >> 6));
    const int ic  = blockIdx.x;
    const int bt  = blockIdx.y;
    const int i0  = ic * ICHUNK_T;
    const int b0  = bt * BT + wid * NB;
    const int e0  = eh * 8;

    float o_reg[NB][8];
    if (iter > 0) {
#pragma unroll
        for (int j = 0; j < NB; ++j) {
            const float4* op = (const float4*)(o_sum + ((size_t)(b0 + j) * NC + c) * NE + e0);
            float4 a = op[0], b = op[1];
            o_reg[j][0] = a.x; o_reg[j][1] = a.y; o_reg[j][2] = a.z; o_reg[j][3] = a.w;
            o_reg[j][4] = b.x; o_reg[j][5] = b.y; o_reg[j][6] = b.z; o_reg[j][7] = b.w;
        }
    }

    float s_acc[NB][8];
#pragma unroll
    for (int j = 0; j < NB; ++j)
#pragma unroll
        for (int e = 0; e < 8; ++e) s_acc[j][e] = 0.f;

    // x(0) prefetch
    const float* xp[NB];
    float4 xnA[NB][2], xnB[NB][2];
#pragma unroll
    for (int j = 0; j < NB; ++j) {
        xp[j] = x + ((size_t)(b0 + j) * NI + i0) * ND;
        xnA[j][0] = *(const float4*)xp[j];
        xnA[j][1] = *(const float4*)(xp[j] + 4);
    }

    const uint* wbase = &Wh[0][c * CROW + e0 * 4];

    auto body = [&](const float4 (&XC)[NB][2], float4 (&XN)[NB][2],
                    int buf, int tp, int II) {
        if (II + 1 < ICHUNK_T) {
#pragma unroll
            for (int j = 0; j < NB; ++j) {
                xp[j] += ND;
                XN[j][0] = *(const float4*)xp[j];
                XN[j][1] = *(const float4*)(xp[j] + 4);
            }
        }

        h2 xq[NB][4];
#pragma unroll
        for (int j = 0; j < NB; ++j) {
            xq[j][0] = cvt_pk(XC[j][0].x, XC[j][0].y);
            xq[j][1] = cvt_pk(XC[j][0].z, XC[j][0].w);
            xq[j][2] = cvt_pk(XC[j][1].x, XC[j][1].y);
            xq[j][3] = cvt_pk(XC[j][1].z, XC[j][1].w);
        }

        // ---- u_hat from resident LDS tile (8 b128, 64 dot2) ----
        const uint* wr = wbase + (buf * GT + tp) * TLDSW;
        float uh[NB][8];
#pragma unroll
        for (int er = 0; er < 8; ++er) {
            uint4 wv = *(const uint4*)(wr + er * 4);
            h2 w0 = u2h(wv.x), w1 = u2h(wv.y), w2 = u2h(wv.z), w3 = u2h(wv.w);
#pragma unroll
            for (int j = 0; j < NB; ++j) {
                float acc = 0.f;
                acc = FDOT2(xq[j][0], w0, acc);
                acc = FDOT2(xq[j][1], w1, acc);
                acc = FDOT2(xq[j][2], w2, acc);
                acc = FDOT2(xq[j][3], w3, acc);
                uh[j][er] = acc;
            }
        }

        if (iter > 0) {
#pragma unroll
            for (int j = 0; j < NB; ++j) {
                float lp = 0.f;
#pragma unroll
                for (int e = 0; e < 8; ++e) lp = fmaf(uh[j][e], o_reg[j][e], lp);
                lp = xor32_sum(lp);
                float el = __expf(lp);
                float v = dpp_add<0x140>(dpp_add<0x141>(
                          dpp_add<0x4E>(dpp_add<0xB1>(el))));
                float den = xor16_sum(v);
                float wgt = el * __builtin_amdgcn_rcpf(den);
#pragma unroll
                for (int e = 0; e < 8; ++e) s_acc[j][e] = fmaf(wgt, uh[j][e], s_acc[j][e]);
            }
        } else {
            const float wgt = 1.f / 32.f;
#pragma unroll
            for (int j = 0; j < NB; ++j)
#pragma unroll
                for (int e = 0; e < 8; ++e) s_acc[j][e] = fmaf(wgt, uh[j][e], s_acc[j][e]);
        }
    };

    // ---- pipelined staging ----
    const uint4* gsrc = (const uint4*)(W_hp + (size_t)i0 * TLDSW);
    uint4 pr[LPT];

    // prologue: load group0 -> regs -> Wh[0]; issue group1 loads
#pragma unroll
    for (int k = 0; k < LPT; ++k) {
        int idx = tid + k * RT_THREADS;
        if (idx < TOT4) pr[k] = gsrc[idx];
    }
#pragma unroll
    for (int k = 0; k < LPT; ++k) {
        int idx = tid + k * RT_THREADS;
        if (idx < TOT4) ((uint4*)Wh[0])[idx] = pr[k];
    }
#pragma unroll
    for (int k = 0; k < LPT; ++k) {
        int idx = tid + k * RT_THREADS;
        if (idx < TOT4) pr[k] = gsrc[TOT4 + idx];
    }
    lds_barrier();

#pragma unroll
    for (int g = 0; g < NG; ++g) {
        const int buf = g & 1;
#pragma unroll
        for (int tp = 0; tp < GT; ++tp) {
            int II = g * GT + tp;
            if ((II & 1) == 0) body(xnA, xnB, buf, tp, II);
            else               body(xnB, xnA, buf, tp, II);
        }
        if (g + 1 < NG) {
            // write group g+1 (loads issued a full group ago; counted vmcnt)
#pragma unroll
            for (int k = 0; k < LPT; ++k) {
                int idx = tid + k * RT_THREADS;
                if (idx < TOT4) ((uint4*)Wh[(g + 1) & 1])[idx] = pr[k];
            }
            // issue group g+2 loads (hide under next group's compute)
            if (g + 2 < NG) {
#pragma unroll
                for (int k = 0; k < LPT; ++k) {
                    int idx = tid + k * RT_THREADS;
                    if (idx < TOT4) pr[k] = gsrc[(size_t)(g + 2) * TOT4 + idx];
                }
            }
            lds_barrier();
        }
    }

    // ---- write partial s (fp16, one slice per ic) ----
#pragma unroll
    for (int j = 0; j < NB; ++j) {
        __half* base = s_part + (((size_t)ic * BATCH + (b0 + j)) * NC + c) * NE + e0;
        union { __half2 h2v[4]; uint4 u; } pk;
#pragma unroll
        for (int q = 0; q < 4; ++q)
            pk.h2v[q] = __floats2half2_rn(s_acc[j][2*q], s_acc[j][2*q+1]);
        *(uint4*)base = pk.u;
    }
}

// ---------------------------------------------------------------------------
// squash: reduce ISPLIT fp16 slices, squash, update o_sum / write output.
// ---------------------------------------------------------------------------
__global__ __launch_bounds__(SQ_THREADS)
void squash_kernel(const __half* __restrict__ s_part, float* __restrict__ o_sum,
                   float* __restrict__ out, int iter)
{
    const int base2 = (blockIdx.x * SQ_THREADS + threadIdx.x) * 2;

    float a0 = 0.f, a1 = 0.f;
#pragma unroll 8
    for (int k = 0; k < ISPLIT; ++k) {
        __half2 v = *(const __half2*)(s_part + (size_t)k * (BATCH * NC * NE) + base2);
        a0 += __low2float(v);
        a1 += __high2float(v);
    }

    float q = sum_over_e8(a0 * a0 + a1 * a1);
    // scale = s2/(1+s2)/sqrt(s2) == sqrt(s2)/(1+s2)
    float scale = sqrtf(q) / (1.f + q);
    float o0 = scale * a0, o1 = scale * a1;

    if (iter == NROUT - 1) {
        *(float2*)(out + base2) = make_float2(o0, o1);
    } else if (iter == 0) {
        *(float2*)(o_sum + base2) = make_float2(o0, o1);
    } else {
        float2 prev = *(float2*)(o_sum + base2);
        *(float2*)(o_sum + base2) = make_float2(prev.x + o0, prev.y + o1);
    }
}

extern "C" void kernel_launch(void* const* d_in, const int* in_sizes, int n_in,
                              void* d_out, int out_size, void* d_ws, size_t ws_size,
                              hipStream_t stream) {
    const float* x = (const float*)d_in[0];   // [128,1152,8]
    const float* W = (const float*)d_in[1];   // [1152,32,8,16]
    float* out = (float*)d_out;               // [128,32,16]

    const size_t whp_words = (size_t)NI * TLDSW;                  // 10.03 MB
    const size_t slice_h   = (size_t)BATCH * NC * NE;             // 65536 halves

    // ws: [W_hp][s_part fp16 x48][o_sum] = ~16.6 MB (ws = 256 MiB confirmed)
    uint*   W_hp   = (uint*)d_ws;
    __half* s_part = (__half*)(W_hp + whp_words);
    float*  o_sum  = (float*)(s_part + (size_t)ISPLIT * slice_h);

    prep_kernel<<<NI / PREP_TPB, RT_THREADS, 0, stream>>>(W, W_hp);

    for (int it = 0; it < NROUT; ++it) {
        route_iter_kernel<<<dim3(ISPLIT, BATCH / BT), RT_THREADS, 0, stream>>>(
            x, W_hp, o_sum, s_part, it);
        squash_kernel<<<(BATCH * NC * NE) / (SQ_THREADS * 2), SQ_THREADS, 0, stream>>>(
            s_part, o_sum, out, it);
    }
}

// Round 26
// 104.779 us; speedup vs baseline: 1.7685x; 1.7685x over previous
//
#include <hip/hip_runtime.h>
#include <hip/hip_fp16.h>
#include <math.h>

// Problem constants (from reference)
#define BATCH 128
#define NI    1152
#define ND    8
#define NC    32
#define NE    16
#define NROUT 3

// Final operating point (proven 105.1 us, round 24):
// prep converts W once -> padded fp16 LDS-image tiles in ws. Route stages
// 6-tile groups into LDS (linear uint4 copy), then barrier-free dot2 bodies
// (NB=2 batches/thread) read W from LDS. 256 thr = 32c x 2eh x 4 wave-groups.
// ISPLIT=48, GTILES=6 (52.2 KB LDS) -> 768 blocks = 3 blocks/CU = 12 waves/CU.
// No launch_bounds min-waves (clamps proved to cause scratch spills).
#define ISPLIT     48
#define GTILES     6
#define BT         8
#define NB         2
#define RT_THREADS 256
#define CROW       68               // words per c row (4c mod 32 -> uniform banks)
#define TLDSW      (NC * CROW)      // 2176 words per padded tile (8704 B)
#define SQ_THREADS 256
#define PREP_TPB   2

typedef _Float16 h2 __attribute__((ext_vector_type(2)));
typedef unsigned int uint;

__device__ __forceinline__ h2 cvt_pk(float a, float b) {
    auto r = __builtin_amdgcn_cvt_pkrtz(a, b);
    union { decltype(r) i; h2 o; } u; u.i = r; return u.o;
}
__device__ __forceinline__ uint h2u(h2 v) { union { h2 h; uint u; } x; x.h = v; return x.u; }
__device__ __forceinline__ h2 u2h(uint v) { union { uint u; h2 h; } x; x.u = v; return x.h; }

#if __has_builtin(__builtin_amdgcn_fdot2)
#define FDOT2(a, b, c) __builtin_amdgcn_fdot2((a), (b), (c), false)
#else
__device__ __forceinline__ float FDOT2(h2 a, h2 b, float c) {
    return c + (float)a.x * (float)b.x + (float)a.y * (float)b.y;
}
#endif

template<int CTRL>
__device__ __forceinline__ float dpp_add(float v) {
    int t = __builtin_amdgcn_update_dpp(0, __float_as_int(v), CTRL, 0xF, 0xF, true);
    return v + __int_as_float(t);
}

__device__ __forceinline__ float xor32_sum(float v) {
#if __has_builtin(__builtin_amdgcn_permlane32_swap)
    auto r = __builtin_amdgcn_permlane32_swap(__float_as_int(v), __float_as_int(v), false, false);
    return __int_as_float(r[0]) + __int_as_float(r[1]);
#else
    return v + __shfl_xor(v, 32);
#endif
}
__device__ __forceinline__ float xor16_sum(float v) {
#if __has_builtin(__builtin_amdgcn_permlane16_swap)
    auto r = __builtin_amdgcn_permlane16_swap(__float_as_int(v), __float_as_int(v), false, false);
    return __int_as_float(r[0]) + __int_as_float(r[1]);
#else
    int s = __builtin_amdgcn_ds_swizzle(__float_as_int(v), 0x401F);
    return v + __int_as_float(s);
#endif
}

__device__ __forceinline__ float sum_over_e8(float v) {
    v = dpp_add<0xB1>(v);
    v = dpp_add<0x4E>(v);
    v = dpp_add<0x141>(v);
    return v;
}

// ---------------------------------------------------------------------------
// prep: W[i][c][d][e] fp32 -> padded fp16 tile image (word c*68 + e*4 + dp).
// ---------------------------------------------------------------------------
__global__ __launch_bounds__(RT_THREADS)
void prep_kernel(const float* __restrict__ W, uint* __restrict__ W_hp)
{
    __shared__ float ls[PREP_TPB][NC * 132];

    const int tid = threadIdx.x;
    const size_t i0 = (size_t)blockIdx.x * PREP_TPB;

    const float4* src = (const float4*)(W + i0 * (NC * ND * NE));
#pragma unroll
    for (int t = 0; t < PREP_TPB; ++t) {
#pragma unroll
        for (int r = 0; r < 4; ++r) {
            int g = tid + r * RT_THREADS;
            float4 v = src[t * 1024 + g];
            *(float4*)&ls[t][(g >> 5) * 132 + (g & 31) * 4] = v;
        }
    }
    __syncthreads();

#pragma unroll
    for (int t = 0; t < PREP_TPB; ++t) {
#pragma unroll
        for (int r = 0; r < 2; ++r) {
            int g = tid + r * RT_THREADS;
            int c = g >> 4, e = g & 15;
            const float* p = &ls[t][c * 132 + e];
            uint4 o;
            o.x = h2u(cvt_pk(p[0],  p[16]));
            o.y = h2u(cvt_pk(p[32], p[48]));
            o.z = h2u(cvt_pk(p[64], p[80]));
            o.w = h2u(cvt_pk(p[96], p[112]));
            *(uint4*)&W_hp[(i0 + t) * TLDSW + c * CROW + e * 4] = o;
        }
    }
}

// ---------------------------------------------------------------------------
// route: stage 6-tile groups (linear uint4 copy), barrier-free dot2 bodies
// with NB=2, all-VALU softmax, fp16 partial s out. Single instantiation.
// ---------------------------------------------------------------------------
__global__ __launch_bounds__(RT_THREADS)
void route_iter_kernel(const float* __restrict__ x, const uint* __restrict__ W_hp,
                       const float* __restrict__ o_sum, __half* __restrict__ s_part,
                       int iter)
{
    constexpr int ICHUNK_T = NI / ISPLIT;          // 24
    constexpr int NGROUP_T = ICHUNK_T / GTILES;    // 4
    static_assert(NGROUP_T * GTILES == ICHUNK_T, "group split");

    __shared__ uint Wh[GTILES * TLDSW];            // 52,224 B -> 3 blocks/CU

    const int tid = threadIdx.x;
    const int c   = tid & 31;
    const int eh  = (tid >> 5) & 1;
    int wid;   // laundered wave id -> x addresses stay on the vector path
    asm("v_mov_b32 %0, %1" : "=v"(wid) : "v"(tid >> 6));
    const int ic  = blockIdx.x;
    const int bt  = blockIdx.y;
    const int i0  = ic * ICHUNK_T;
    const int b0  = bt * BT + wid * NB;
    const int e0  = eh * 8;

    float o_reg[NB][8];
    if (iter > 0) {
#pragma unroll
        for (int j = 0; j < NB; ++j) {
            const float4* op = (const float4*)(o_sum + ((size_t)(b0 + j) * NC + c) * NE + e0);
            float4 a = op[0], b = op[1];
            o_reg[j][0] = a.x; o_reg[j][1] = a.y; o_reg[j][2] = a.z; o_reg[j][3] = a.w;
            o_reg[j][4] = b.x; o_reg[j][5] = b.y; o_reg[j][6] = b.z; o_reg[j][7] = b.w;
        }
    }

    float s_acc[NB][8];
#pragma unroll
    for (int j = 0; j < NB; ++j)
#pragma unroll
        for (int e = 0; e < 8; ++e) s_acc[j][e] = 0.f;

    // x(0) prefetch
    const float* xp[NB];
    float4 xnA[NB][2], xnB[NB][2];
#pragma unroll
    for (int j = 0; j < NB; ++j) {
        xp[j] = x + ((size_t)(b0 + j) * NI + i0) * ND;
        xnA[j][0] = *(const float4*)xp[j];
        xnA[j][1] = *(const float4*)(xp[j] + 4);
    }

    const uint* wbase = &Wh[c * CROW + e0 * 4];

    auto body = [&](const float4 (&XC)[NB][2], float4 (&XN)[NB][2], int t, int II) {
        if (II + 1 < ICHUNK_T) {
#pragma unroll
            for (int j = 0; j < NB; ++j) {
                xp[j] += ND;
                XN[j][0] = *(const float4*)xp[j];
                XN[j][1] = *(const float4*)(xp[j] + 4);
            }
        }

        h2 xq[NB][4];
#pragma unroll
        for (int j = 0; j < NB; ++j) {
            xq[j][0] = cvt_pk(XC[j][0].x, XC[j][0].y);
            xq[j][1] = cvt_pk(XC[j][0].z, XC[j][0].w);
            xq[j][2] = cvt_pk(XC[j][1].x, XC[j][1].y);
            xq[j][3] = cvt_pk(XC[j][1].z, XC[j][1].w);
        }

        // ---- u_hat from resident LDS tile t (8 b128, 64 dot2) ----
        const uint* wr = wbase + t * TLDSW;
        float uh[NB][8];
#pragma unroll
        for (int er = 0; er < 8; ++er) {
            uint4 wv = *(const uint4*)(wr + er * 4);
            h2 w0 = u2h(wv.x), w1 = u2h(wv.y), w2 = u2h(wv.z), w3 = u2h(wv.w);
#pragma unroll
            for (int j = 0; j < NB; ++j) {
                float acc = 0.f;
                acc = FDOT2(xq[j][0], w0, acc);
                acc = FDOT2(xq[j][1], w1, acc);
                acc = FDOT2(xq[j][2], w2, acc);
                acc = FDOT2(xq[j][3], w3, acc);
                uh[j][er] = acc;
            }
        }

        if (iter > 0) {
#pragma unroll
            for (int j = 0; j < NB; ++j) {
                float lp = 0.f;
#pragma unroll
                for (int e = 0; e < 8; ++e) lp = fmaf(uh[j][e], o_reg[j][e], lp);
                lp = xor32_sum(lp);
                float el = __expf(lp);
                float v = dpp_add<0x140>(dpp_add<0x141>(
                          dpp_add<0x4E>(dpp_add<0xB1>(el))));
                float den = xor16_sum(v);
                float wgt = el * __builtin_amdgcn_rcpf(den);
#pragma unroll
                for (int e = 0; e < 8; ++e) s_acc[j][e] = fmaf(wgt, uh[j][e], s_acc[j][e]);
            }
        } else {
            const float wgt = 1.f / 32.f;
#pragma unroll
            for (int j = 0; j < NB; ++j)
#pragma unroll
                for (int e = 0; e < 8; ++e) s_acc[j][e] = fmaf(wgt, uh[j][e], s_acc[j][e]);
        }
    };

    // groups: {stage GTILES tiles (linear copy), sync, GTILES bodies}
#pragma unroll
    for (int g = 0; g < NGROUP_T; ++g) {
        if (g) __syncthreads();
        {
            constexpr int TOT4 = GTILES * TLDSW / 4;   // 3264
            const uint4* src = (const uint4*)(W_hp + (size_t)(i0 + g * GTILES) * TLDSW);
            uint4* dst = (uint4*)Wh;
#pragma unroll
            for (int k = 0; k < (TOT4 + RT_THREADS - 1) / RT_THREADS; ++k) {
                int idx = tid + k * RT_THREADS;
                if (TOT4 % RT_THREADS == 0 || idx < TOT4)
                    dst[idx] = src[idx];
            }
        }
        __syncthreads();

#pragma unroll
        for (int tp = 0; tp < GTILES; ++tp) {
            int II = g * GTILES + tp;
            if ((II & 1) == 0) body(xnA, xnB, tp, II);
            else               body(xnB, xnA, tp, II);
        }
    }

    // ---- write partial s (fp16, one slice per ic) ----
#pragma unroll
    for (int j = 0; j < NB; ++j) {
        __half* base = s_part + (((size_t)ic * BATCH + (b0 + j)) * NC + c) * NE + e0;
        union { __half2 h2v[4]; uint4 u; } pk;
#pragma unroll
        for (int q = 0; q < 4; ++q)
            pk.h2v[q] = __floats2half2_rn(s_acc[j][2*q], s_acc[j][2*q+1]);
        *(uint4*)base = pk.u;
    }
}

// ---------------------------------------------------------------------------
// squash: reduce ISPLIT fp16 slices, squash, update o_sum / write output.
// ---------------------------------------------------------------------------
__global__ __launch_bounds__(SQ_THREADS)
void squash_kernel(const __half* __restrict__ s_part, float* __restrict__ o_sum,
                   float* __restrict__ out, int iter)
{
    const int base2 = (blockIdx.x * SQ_THREADS + threadIdx.x) * 2;

    float a0 = 0.f, a1 = 0.f;
#pragma unroll 8
    for (int k = 0; k < ISPLIT; ++k) {
        __half2 v = *(const __half2*)(s_part + (size_t)k * (BATCH * NC * NE) + base2);
        a0 += __low2float(v);
        a1 += __high2float(v);
    }

    float q = sum_over_e8(a0 * a0 + a1 * a1);
    // scale = s2/(1+s2)/sqrt(s2) == sqrt(s2)/(1+s2)
    float scale = sqrtf(q) / (1.f + q);
    float o0 = scale * a0, o1 = scale * a1;

    if (iter == NROUT - 1) {
        *(float2*)(out + base2) = make_float2(o0, o1);
    } else if (iter == 0) {
        *(float2*)(o_sum + base2) = make_float2(o0, o1);
    } else {
        float2 prev = *(float2*)(o_sum + base2);
        *(float2*)(o_sum + base2) = make_float2(prev.x + o0, prev.y + o1);
    }
}

extern "C" void kernel_launch(void* const* d_in, const int* in_sizes, int n_in,
                              void* d_out, int out_size, void* d_ws, size_t ws_size,
                              hipStream_t stream) {
    const float* x = (const float*)d_in[0];   // [128,1152,8]
    const float* W = (const float*)d_in[1];   // [1152,32,8,16]
    float* out = (float*)d_out;               // [128,32,16]

    const size_t whp_words = (size_t)NI * TLDSW;                  // 10.03 MB
    const size_t slice_h   = (size_t)BATCH * NC * NE;             // 65536 halves

    // ws: [W_hp][s_part fp16 x48][o_sum] = ~16.6 MB (ws = 256 MiB confirmed)
    uint*   W_hp   = (uint*)d_ws;
    __half* s_part = (__half*)(W_hp + whp_words);
    float*  o_sum  = (float*)(s_part + (size_t)ISPLIT * slice_h);

    prep_kernel<<<NI / PREP_TPB, RT_THREADS, 0, stream>>>(W, W_hp);

    for (int it = 0; it < NROUT; ++it) {
        route_iter_kernel<<<dim3(ISPLIT, BATCH / BT), RT_THREADS, 0, stream>>>(
            x, W_hp, o_sum, s_part, it);
        squash_kernel<<<(BATCH * NC * NE) / (SQ_THREADS * 2), SQ_THREADS, 0, stream>>>(
            s_part, o_sum, out, it);
    }
}